// Round 9
// baseline (191.631 us; speedup 1.0000x reference)
//
#include <hip/hip_runtime.h>
#include <hip/hip_bf16.h>
#include <math.h>

#define BB 4
#define TT 4096
#define DD 1024
#define HH 64
#define MTOT (BB * TT)   // 16384 rows
#define LD 72            // padded LDS row stride (shorts), 144 B = 16B-aligned
#define NCH 4            // key chunks per q row-block (1024 keys each)
#define ALD 1032         // qkv x-tile LDS row stride (shorts): 1024 + 8 pad

typedef short short8 __attribute__((ext_vector_type(8)));
typedef float f32x4  __attribute__((ext_vector_type(4)));

__device__ __forceinline__ unsigned short f2bf(float f) {
    unsigned u = __builtin_bit_cast(unsigned, f);
    unsigned r = (u + 0x7fffu + ((u >> 16) & 1u)) >> 16;
    return (unsigned short)r;
}

__device__ __forceinline__ unsigned long long pack4(float a, float b, float c, float d) {
    return (unsigned long long)f2bf(a) |
           ((unsigned long long)f2bf(b) << 16) |
           ((unsigned long long)f2bf(c) << 32) |
           ((unsigned long long)f2bf(d) << 48);
}

__device__ __forceinline__ short8 pack8(float4 a, float4 b) {
    short8 r;
    r[0] = (short)f2bf(a.x); r[1] = (short)f2bf(a.y);
    r[2] = (short)f2bf(a.z); r[3] = (short)f2bf(a.w);
    r[4] = (short)f2bf(b.x); r[5] = (short)f2bf(b.y);
    r[6] = (short)f2bf(b.z); r[7] = (short)f2bf(b.w);
    return r;
}

// Workspace layout — byte-identical to R3/R4/R6-R8 passing rounds
#define QOFF  0
#define KOFF  (MTOT * HH)
#define VOFF  (2 * MTOT * HH)
#define BF_TOTAL (3 * MTOT * HH)

// ---------------------------------------------------------------------------
// Kernel 0: transpose W (1024x64 fp32) -> Wt (64x1024 bf16), 3 matrices.
// (proven R2-R8, verbatim)
// ---------------------------------------------------------------------------
__global__ __launch_bounds__(256) void transpose_w(
    const float* __restrict__ Wq, const float* __restrict__ Wk,
    const float* __restrict__ Wv, unsigned short* __restrict__ Wt)
{
    const int w = blockIdx.y;
    const float* W = (w == 0) ? Wq : (w == 1) ? Wk : Wv;
    unsigned short* o = Wt + (size_t)w * 64 * 1024;
    const int t  = threadIdx.x;
    const int n4 = t & 15;
    const int k0 = blockIdx.x * 64 + (t >> 4) * 4;

    float v[4][4];
#pragma unroll
    for (int ii = 0; ii < 4; ++ii) {
        float4 r = *(const float4*)&W[(size_t)(k0 + ii) * HH + n4 * 4];
        v[ii][0] = r.x; v[ii][1] = r.y; v[ii][2] = r.z; v[ii][3] = r.w;
    }
#pragma unroll
    for (int cc = 0; cc < 4; ++cc) {
        unsigned long long pk = pack4(v[0][cc], v[1][cc], v[2][cc], v[3][cc]);
        *(unsigned long long*)&o[(size_t)(n4 * 4 + cc) * 1024 + k0] = pk;
    }
}

// ---------------------------------------------------------------------------
// Kernel 1: fused QKV projection, x-stationary two-phase.
// Grid 512 x 512 thr (8 waves).  Block = 32 rows x 192 cols.
// Phase 1: stream x rows -> LDS bf16 (pure copy pattern -> HBM-rate).
// Phase 2: barrier-free unrolled k-loop: A from LDS, B straight from
// L2-resident Wt (384 KB, shared by all blocks), 3 MFMA/step/wave.
// Wave = (strip in 0..1) x (col-tile triple in 0..3).
// ---------------------------------------------------------------------------
__global__ __launch_bounds__(512, 4) void qkv_proj(
    const float* __restrict__ x,
    const unsigned short* __restrict__ Wt,
    unsigned short* __restrict__ qkv)
{
    const int tid   = threadIdx.x;
    const int lane  = tid & 63;
    const int wave  = tid >> 6;      // 0..7
    const int l15   = lane & 15;
    const int quad  = lane >> 4;
    const int m0    = blockIdx.x * 32;
    const int strip = wave & 1;      // 16-row strip
    const int tri   = wave >> 1;     // col-tile triple (3 of 12)

    __shared__ unsigned short Axl[32 * ALD];   // [row][k] bf16, 66 KB

    // ---- Phase 1: x (fp32, 128 KB) -> LDS bf16. Coalesced copy stream.
    {
        const int prow = tid >> 4;   // 0..31
        const int pseg = tid & 15;   // 16B-seg id
        const float* xrow = x + (size_t)(m0 + prow) * DD;
        unsigned short* arow = &Axl[prow * ALD];
#pragma unroll
        for (int i = 0; i < 8; ++i) {
            int k0 = pseg * 8 + i * 128;
            float4 a0 = *(const float4*)(xrow + k0);
            float4 a1 = *(const float4*)(xrow + k0 + 4);
            *(short8*)&arow[k0] = pack8(a0, a1);
        }
    }
    __syncthreads();

    // ---- Phase 2: barrier-free k-loop. B from L2 (Wt hot), A from LDS.
    const unsigned short* wp0;
    const unsigned short* wp1;
    const unsigned short* wp2;
    {
        int g0 = tri * 3;
        wp0 = Wt + (size_t)((g0 + 0) >> 2) * 65536 + (size_t)(((g0 + 0) & 3) * 16 + l15) * 1024 + quad * 8;
        wp1 = Wt + (size_t)((g0 + 1) >> 2) * 65536 + (size_t)(((g0 + 1) & 3) * 16 + l15) * 1024 + quad * 8;
        wp2 = Wt + (size_t)((g0 + 2) >> 2) * 65536 + (size_t)(((g0 + 2) & 3) * 16 + l15) * 1024 + quad * 8;
    }
    const unsigned short* arl = &Axl[(strip * 16 + l15) * ALD + quad * 8];

    f32x4 acc[3];
#pragma unroll
    for (int i = 0; i < 3; ++i) acc[i] = (f32x4){0.f, 0.f, 0.f, 0.f};

#pragma unroll
    for (int s = 0; s < 32; ++s) {
        short8 af = *(const short8*)(arl + s * 32);       // ds_read_b128
        short8 b0 = *(const short8*)(wp0 + s * 32);       // global, imm offsets
        short8 b1 = *(const short8*)(wp1 + s * 32);
        short8 b2 = *(const short8*)(wp2 + s * 32);
        acc[0] = __builtin_amdgcn_mfma_f32_16x16x32_bf16(af, b0, acc[0], 0, 0, 0);
        acc[1] = __builtin_amdgcn_mfma_f32_16x16x32_bf16(af, b1, acc[1], 0, 0, 0);
        acc[2] = __builtin_amdgcn_mfma_f32_16x16x32_bf16(af, b2, acc[2], 0, 0, 0);
    }

    // ---- epilogue: q/k as [b t h] bf16, v transposed [b h t] bf16
    unsigned short* q_bf  = qkv + QOFF;
    unsigned short* k_bf  = qkv + KOFF;
    unsigned short* vt_bf = qkv + VOFF;
#pragma unroll
    for (int i = 0; i < 3; ++i) {
        int g = tri * 3 + i, w = g >> 2, col = (g & 3) * 16 + l15;
#pragma unroll
        for (int r = 0; r < 4; ++r) {
            int m = m0 + strip * 16 + quad * 4 + r;
            unsigned short bv = f2bf(acc[i][r]);
            if (w == 0)      q_bf[(size_t)m * HH + col] = bv;
            else if (w == 1) k_bf[(size_t)m * HH + col] = bv;
            else {
                int b = m >> 12, t = m & 4095;
                vt_bf[(size_t)b * HH * TT + (size_t)col * TT + t] = bv;
            }
        }
    }
}

// ---------------------------------------------------------------------------
// Kernel 2: causal flash attention, key-split NCH=4, 2-tile staging rounds.
// (byte-identical to passing R6-R8)
// ---------------------------------------------------------------------------
__global__ __launch_bounds__(256) void flash_attn(
    const unsigned short* __restrict__ qkv,
    float* __restrict__ Opart,
    float* __restrict__ Mpart,
    float* __restrict__ Lpart)
{
    const int qt = 63 - blockIdx.x;   // heavy blocks dispatch first
    const int b  = blockIdx.y;
    const int c  = blockIdx.z;
    if (c * 16 > qt) return;
    const int j0   = c * 16;
    const int jmax = min(j0 + 16, qt + 1);

    const int tid  = threadIdx.x;
    const int lane = tid & 63;
    const int wave = tid >> 6;
    const int l15  = lane & 15;
    const int quad = lane >> 4;

    const unsigned short* q_g  = qkv + QOFF + (size_t)b * TT * HH;
    const unsigned short* k_g  = qkv + KOFF + (size_t)b * TT * HH;
    const unsigned short* vt_g = qkv + VOFF + (size_t)b * HH * TT;

    __shared__ unsigned short Ks[128 * LD];     // 2 K tiles, [key][h], stride 72
    __shared__ unsigned short Vs[64 * 136];     // V^T, [h][2*64 keys], stride 136
    __shared__ unsigned short Ps[4 * 16 * LD];  // per-wave P strips
    unsigned short* Pw = Ps + wave * 16 * LD;

    short8 qf[2];
#pragma unroll
    for (int kk = 0; kk < 2; ++kk)
        qf[kk] = *(const short8*)&q_g[(size_t)(qt * 64 + wave * 16 + l15) * HH + kk * 32 + quad * 8];

    f32x4 ov[4];
#pragma unroll
    for (int i = 0; i < 4; ++i) ov[i] = (f32x4){0.f, 0.f, 0.f, 0.f};
    float m_run = -1e30f, l_run = 0.f;

    const int srow = tid >> 3;   // 0..31
    const int seg  = tid & 7;    // 16B segment

    const float SC = 0.125f * 1.44269504088896f;   // scale * log2(e)

    for (int jr = j0; jr < jmax; jr += 2) {
        const int nrow = min(jmax - jr, 2) * 64;   // 64 or 128 keys this round
        __syncthreads();   // all waves done reading previous round's Ks/Vs

#pragma unroll
        for (int r4 = 0; r4 < 4; ++r4) {
            int row = srow + r4 * 32;
            if (row < nrow)
                *(ulonglong2*)&Ks[row * LD + seg * 8] =
                    *(const ulonglong2*)&k_g[(size_t)(jr * 64 + row) * HH + seg * 8];
        }
#pragma unroll
        for (int c2 = 0; c2 < 2; ++c2) {
            int chunk = seg + c2 * 8;            // 0..15
            if (chunk * 8 < nrow) {
#pragma unroll
                for (int r2 = 0; r2 < 2; ++r2) {
                    int h = srow + r2 * 32;
                    *(ulonglong2*)&Vs[h * 136 + chunk * 8] =
                        *(const ulonglong2*)&vt_g[(size_t)h * TT + jr * 64 + chunk * 8];
                }
            }
        }
        __syncthreads();

        const int jend = min(jr + 2, jmax);
        for (int j = jr; j < jend; ++j) {
            const int tl = (j - jr) * 64;

            f32x4 st[4];
#pragma unroll
            for (int i = 0; i < 4; ++i) st[i] = (f32x4){0.f, 0.f, 0.f, 0.f};
#pragma unroll
            for (int kk = 0; kk < 2; ++kk)
#pragma unroll
                for (int mt = 0; mt < 4; ++mt) {
                    short8 a = *(const short8*)&Ks[(tl + mt * 16 + l15) * LD + kk * 32 + quad * 8];
                    st[mt] = __builtin_amdgcn_mfma_f32_16x16x32_bf16(a, qf[kk], st[mt], 0, 0, 0);
                }

#pragma unroll
            for (int mt = 0; mt < 4; ++mt)
#pragma unroll
                for (int r = 0; r < 4; ++r) st[mt][r] *= SC;
            if (j == qt) {
                int qg = wave * 16 + l15;
#pragma unroll
                for (int mt = 0; mt < 4; ++mt)
#pragma unroll
                    for (int r = 0; r < 4; ++r)
                        if (mt * 16 + quad * 4 + r > qg) st[mt][r] = -1e30f;
            }

            float mloc = -1e30f;
#pragma unroll
            for (int mt = 0; mt < 4; ++mt)
#pragma unroll
                for (int r = 0; r < 4; ++r) mloc = fmaxf(mloc, st[mt][r]);
            mloc = fmaxf(mloc, __shfl_xor(mloc, 16));
            mloc = fmaxf(mloc, __shfl_xor(mloc, 32));
            float m_new = fmaxf(m_run, mloc);
            float alpha = exp2f(m_run - m_new);
            m_run = m_new;

            float ssum = 0.f;
#pragma unroll
            for (int mt = 0; mt < 4; ++mt)
#pragma unroll
                for (int r = 0; r < 4; ++r) {
                    float p = exp2f(st[mt][r] - m_new);
                    st[mt][r] = p;
                    ssum += p;
                }
            ssum += __shfl_xor(ssum, 16);
            ssum += __shfl_xor(ssum, 32);
            l_run = l_run * alpha + ssum;

#pragma unroll
            for (int mt = 0; mt < 4; ++mt)
                *(unsigned long long*)&Pw[l15 * LD + mt * 16 + quad * 4] =
                    pack4(st[mt][0], st[mt][1], st[mt][2], st[mt][3]);

            float a4[4];
#pragma unroll
            for (int r = 0; r < 4; ++r) a4[r] = __shfl(alpha, quad * 4 + r);
#pragma unroll
            for (int ht = 0; ht < 4; ++ht)
#pragma unroll
                for (int r = 0; r < 4; ++r) ov[ht][r] *= a4[r];

#pragma unroll
            for (int kk = 0; kk < 2; ++kk) {
                short8 a = *(const short8*)&Pw[l15 * LD + kk * 32 + quad * 8];
#pragma unroll
                for (int ht = 0; ht < 4; ++ht) {
                    short8 bf = *(const short8*)&Vs[(ht * 16 + l15) * 136 + tl + kk * 32 + quad * 8];
                    ov[ht] = __builtin_amdgcn_mfma_f32_16x16x32_bf16(a, bf, ov[ht], 0, 0, 0);
                }
            }
        }
    }

    float* Ob = Opart + ((size_t)((b * 64 + qt) * NCH + c)) * 4096;
#pragma unroll
    for (int ht = 0; ht < 4; ++ht)
#pragma unroll
        for (int r = 0; r < 4; ++r)
            Ob[(size_t)(wave * 16 + quad * 4 + r) * HH + ht * 16 + l15] = ov[ht][r];
    if (quad == 0) {
        size_t mi = (size_t)((b * 64 + qt) * NCH + c) * 64 + wave * 16 + l15;
        Mpart[mi] = m_run;
        Lpart[mi] = l_run;
    }
}

// ---------------------------------------------------------------------------
// Kernel 3: combine partials (exp2 domain), normalize, write fp32 out.
// (proven R4/R6-R8, verbatim)
// ---------------------------------------------------------------------------
__global__ __launch_bounds__(256) void combine(
    const float* __restrict__ Opart,
    const float* __restrict__ Mpart,
    const float* __restrict__ Lpart,
    float* __restrict__ out)
{
    const int qt = blockIdx.x;
    const int b  = blockIdx.y;
    const int nc = (qt >> 4) + 1;
    const int t  = threadIdx.x;
    const int row = t >> 2;
    const int seg = t & 3;

    const size_t base = (size_t)(b * 64 + qt) * NCH;

    float m_c[NCH], M = -1e30f;
    for (int c = 0; c < nc; ++c) {
        m_c[c] = Mpart[(base + c) * 64 + row];
        M = fmaxf(M, m_c[c]);
    }
    float L = 0.f, w_c[NCH];
    for (int c = 0; c < nc; ++c) {
        w_c[c] = exp2f(m_c[c] - M);
        L += w_c[c] * Lpart[(base + c) * 64 + row];
    }
    float invL = 1.0f / L;

    f32x4 o[4];
#pragma unroll
    for (int i = 0; i < 4; ++i) o[i] = (f32x4){0.f, 0.f, 0.f, 0.f};
    for (int c = 0; c < nc; ++c) {
        const float* Ob = Opart + (base + c) * 4096 + (size_t)row * HH + seg * 16;
#pragma unroll
        for (int i = 0; i < 4; ++i) {
            f32x4 v = *(const f32x4*)(Ob + i * 4);
            o[i] += v * w_c[c];
        }
    }
    float* op = out + ((size_t)b * TT + qt * 64 + row) * HH + seg * 16;
#pragma unroll
    for (int i = 0; i < 4; ++i)
        *(f32x4*)(op + i * 4) = o[i] * invL;
}

extern "C" void kernel_launch(void* const* d_in, const int* in_sizes, int n_in,
                              void* d_out, int out_size, void* d_ws, size_t ws_size,
                              hipStream_t stream) {
    const float* x  = (const float*)d_in[0];
    const float* Wq = (const float*)d_in[1];
    const float* Wk = (const float*)d_in[2];
    const float* Wv = (const float*)d_in[3];
    float* out = (float*)d_out;

    unsigned short* qkv = (unsigned short*)d_ws;                 // 6.29 MB bf16
    float* Opart = (float*)((char*)d_ws + BF_TOTAL * 2);         // 16.78 MB fp32
    float* Mpart = Opart + (size_t)BB * 64 * NCH * 4096;         // 0.26 MB
    float* Lpart = Mpart + (size_t)BB * 64 * NCH * 64;           // 0.26 MB

    unsigned short* Wt = (unsigned short*)d_out;  // pre-scratch; combine overwrites

    transpose_w<<<dim3(16, 3), 256, 0, stream>>>(Wq, Wk, Wv, Wt);
    qkv_proj<<<dim3(MTOT / 32), 512, 0, stream>>>(x, Wt, qkv);
    flash_attn<<<dim3(64, BB, NCH), 256, 0, stream>>>(qkv, Opart, Mpart, Lpart);
    combine<<<dim3(64, BB), 256, 0, stream>>>(Opart, Mpart, Lpart, out);
}

// Round 10
// 167.788 us; speedup vs baseline: 1.1421x; 1.1421x over previous
//
#include <hip/hip_runtime.h>
#include <hip/hip_bf16.h>
#include <math.h>

#define BB 4
#define TT 4096
#define DD 1024
#define HH 64
#define MTOT (BB * TT)   // 16384 rows
#define LD 72            // padded LDS row stride (shorts), 144 B = 16B-aligned
#define NCH 4            // key chunks per q row-block (1024 keys each)

typedef short short8 __attribute__((ext_vector_type(8)));
typedef float f32x4  __attribute__((ext_vector_type(4)));
typedef unsigned int u32;

__device__ __forceinline__ unsigned short f2bf(float f) {
    unsigned u = __builtin_bit_cast(unsigned, f);
    unsigned r = (u + 0x7fffu + ((u >> 16) & 1u)) >> 16;
    return (unsigned short)r;
}

__device__ __forceinline__ unsigned long long pack4(float a, float b, float c, float d) {
    return (unsigned long long)f2bf(a) |
           ((unsigned long long)f2bf(b) << 16) |
           ((unsigned long long)f2bf(c) << 32) |
           ((unsigned long long)f2bf(d) << 48);
}

__device__ __forceinline__ short8 pack8(float4 a, float4 b) {
    short8 r;
    r[0] = (short)f2bf(a.x); r[1] = (short)f2bf(a.y);
    r[2] = (short)f2bf(a.z); r[3] = (short)f2bf(a.w);
    r[4] = (short)f2bf(b.x); r[5] = (short)f2bf(b.y);
    r[6] = (short)f2bf(b.z); r[7] = (short)f2bf(b.w);
    return r;
}

// async global->LDS DMA, 16B/lane; lds dest = wave-uniform base + lane*16
__device__ __forceinline__ void gl16(const void* g, void* l) {
    __builtin_amdgcn_global_load_lds(
        (const __attribute__((address_space(1))) u32*)g,
        (__attribute__((address_space(3))) u32*)l, 16, 0, 0);
}

// Workspace layout — byte-identical to R3/R4/R6-R9 passing rounds
#define QOFF  0
#define KOFF  (MTOT * HH)
#define VOFF  (2 * MTOT * HH)
#define BF_TOTAL (3 * MTOT * HH)

// ---------------------------------------------------------------------------
// Kernel 0: transpose W (1024x64 fp32) -> Wt (64x1024 bf16), 3 matrices.
// (proven R2-R9, verbatim)
// ---------------------------------------------------------------------------
__global__ __launch_bounds__(256) void transpose_w(
    const float* __restrict__ Wq, const float* __restrict__ Wk,
    const float* __restrict__ Wv, unsigned short* __restrict__ Wt)
{
    const int w = blockIdx.y;
    const float* W = (w == 0) ? Wq : (w == 1) ? Wk : Wv;
    unsigned short* o = Wt + (size_t)w * 64 * 1024;
    const int t  = threadIdx.x;
    const int n4 = t & 15;
    const int k0 = blockIdx.x * 64 + (t >> 4) * 4;

    float v[4][4];
#pragma unroll
    for (int ii = 0; ii < 4; ++ii) {
        float4 r = *(const float4*)&W[(size_t)(k0 + ii) * HH + n4 * 4];
        v[ii][0] = r.x; v[ii][1] = r.y; v[ii][2] = r.z; v[ii][3] = r.w;
    }
#pragma unroll
    for (int cc = 0; cc < 4; ++cc) {
        unsigned long long pk = pack4(v[0][cc], v[1][cc], v[2][cc], v[3][cc]);
        *(unsigned long long*)&o[(size_t)(n4 * 4 + cc) * 1024 + k0] = pk;
    }
}

// ---------------------------------------------------------------------------
// Kernel 1: fused QKV projection — m97-style global_load_lds DMA K-loop.
// C[16384,192] = x @ [Wq|Wk|Wv].  Grid 512 x 256 thr; block = 32 rows x 192
// cols; BK=64; double-buffered LDS (A fp32 8KB, B bf16 24KB per buffer =
// 64 KB -> 2 blocks/CU).  Staging is pure DMA (no VGPR round-trip): all 8
// instrs/wave issue back-to-back, one vmcnt drain at the barrier.  DMA dest
// is contiguous (lane*16), so a lane-side XOR *source* swizzle (chunk ^=
// row&15 for A, ^= col&7 for B) is applied and inverted at ds_read time,
// making fragment reads 2 lanes/bank-group (= free, m136).
// Wave = (strip = wave&1: 16 rows) x (half = wave>>1: 6 col-tiles).
// ---------------------------------------------------------------------------
__global__ __launch_bounds__(256, 2) void qkv_proj(
    const float* __restrict__ x,
    const unsigned short* __restrict__ Wt,
    unsigned short* __restrict__ qkv)
{
    const int tid   = threadIdx.x;
    const int lane  = tid & 63;
    const int wave  = tid >> 6;      // 0..3
    const int l15   = lane & 15;
    const int quad  = lane >> 4;
    const int m0    = blockIdx.x * 32;
    const int strip = wave & 1;
    const int half  = wave >> 1;

    __shared__ float          Af[2][32 * 64];    // [row][k] fp32, raw (DMA)
    __shared__ unsigned short Bs[2][192 * 64];   // [col][k] bf16, raw (DMA)

    // DMA lane decomposition (constant per thread)
    const int ar  = lane >> 4;             // A: row within 4-row instr group
    const int as  = lane & 15;             // A: dest 16B chunk
    const int bc  = lane >> 3;             // B: col within 8-col instr group
    const int bs2 = (lane & 7) ^ bc;       // B: swizzled source chunk

    // stage BK=64 slab `it` into buffer p: 2 A-instrs + 6 B-instrs per wave
#define STAGE(it, p)                                                         \
    {                                                                        \
        const int kc_ = (it) * 64;                                           \
        _Pragma("unroll")                                                    \
        for (int jj = 0; jj < 2; ++jj) {                                     \
            int j   = wave * 2 + jj;                                         \
            int row = 4 * j + ar;                                            \
            int sw  = as ^ (row & 15);                                       \
            gl16(x + (size_t)(m0 + row) * DD + kc_ + sw * 4,                 \
                 &Af[p][j * 256]);                                           \
        }                                                                    \
        _Pragma("unroll")                                                    \
        for (int jj = 0; jj < 6; ++jj) {                                     \
            int j    = wave * 6 + jj;                                        \
            int gcol = 8 * j + bc;                                           \
            gl16(Wt + (size_t)gcol * 1024 + kc_ + bs2 * 8,                   \
                 &Bs[p][j * 512]);                                           \
        }                                                                    \
    }

    f32x4 acc[6];
#pragma unroll
    for (int i = 0; i < 6; ++i) acc[i] = (f32x4){0.f, 0.f, 0.f, 0.f};

    STAGE(0, 0)
    __syncthreads();   // compiler drains vmcnt(0) before barrier
    int p = 0;

    for (int it = 0; it < 16; ++it) {
        if (it < 15) STAGE(it + 1, p ^ 1)    // async DMA, flies during compute

        const int row = strip * 16 + l15;
#pragma unroll
        for (int ks = 0; ks < 2; ++ks) {
            int c0 = ks * 8 + quad * 2;
            float4 a0 = *(const float4*)&Af[p][row * 64 + ((c0)     ^ l15) * 4];
            float4 a1 = *(const float4*)&Af[p][row * 64 + ((c0 + 1) ^ l15) * 4];
            short8 af = pack8(a0, a1);
            int cb = (ks * 4 + quad) ^ (l15 & 7);
#pragma unroll
            for (int jj = 0; jj < 6; ++jj) {
                int col = (half * 6 + jj) * 16 + l15;
                short8 bfr = *(const short8*)&Bs[p][col * 64 + cb * 8];
                acc[jj] = __builtin_amdgcn_mfma_f32_16x16x32_bf16(af, bfr, acc[jj], 0, 0, 0);
            }
        }
        __syncthreads();   // drains next slab's DMA + releases buf p
        p ^= 1;
    }
#undef STAGE

    // ---- epilogue: q/k as [b t h] bf16, v transposed [b h t] bf16
    unsigned short* q_bf  = qkv + QOFF;
    unsigned short* k_bf  = qkv + KOFF;
    unsigned short* vt_bf = qkv + VOFF;
#pragma unroll
    for (int jj = 0; jj < 6; ++jj) {
        int g = half * 6 + jj, w = g >> 2, col = (g & 3) * 16 + l15;
#pragma unroll
        for (int r = 0; r < 4; ++r) {
            int m = m0 + strip * 16 + quad * 4 + r;
            unsigned short bv = f2bf(acc[jj][r]);
            if (w == 0)      q_bf[(size_t)m * HH + col] = bv;
            else if (w == 1) k_bf[(size_t)m * HH + col] = bv;
            else {
                int b = m >> 12, t = m & 4095;
                vt_bf[(size_t)b * HH * TT + (size_t)col * TT + t] = bv;
            }
        }
    }
}

// ---------------------------------------------------------------------------
// Kernel 2: causal flash attention, key-split NCH=4, 2-tile staging rounds.
// (byte-identical to passing R6-R9)
// ---------------------------------------------------------------------------
__global__ __launch_bounds__(256) void flash_attn(
    const unsigned short* __restrict__ qkv,
    float* __restrict__ Opart,
    float* __restrict__ Mpart,
    float* __restrict__ Lpart)
{
    const int qt = 63 - blockIdx.x;   // heavy blocks dispatch first
    const int b  = blockIdx.y;
    const int c  = blockIdx.z;
    if (c * 16 > qt) return;
    const int j0   = c * 16;
    const int jmax = min(j0 + 16, qt + 1);

    const int tid  = threadIdx.x;
    const int lane = tid & 63;
    const int wave = tid >> 6;
    const int l15  = lane & 15;
    const int quad = lane >> 4;

    const unsigned short* q_g  = qkv + QOFF + (size_t)b * TT * HH;
    const unsigned short* k_g  = qkv + KOFF + (size_t)b * TT * HH;
    const unsigned short* vt_g = qkv + VOFF + (size_t)b * HH * TT;

    __shared__ unsigned short Ks[128 * LD];     // 2 K tiles, [key][h], stride 72
    __shared__ unsigned short Vs[64 * 136];     // V^T, [h][2*64 keys], stride 136
    __shared__ unsigned short Ps[4 * 16 * LD];  // per-wave P strips
    unsigned short* Pw = Ps + wave * 16 * LD;

    short8 qf[2];
#pragma unroll
    for (int kk = 0; kk < 2; ++kk)
        qf[kk] = *(const short8*)&q_g[(size_t)(qt * 64 + wave * 16 + l15) * HH + kk * 32 + quad * 8];

    f32x4 ov[4];
#pragma unroll
    for (int i = 0; i < 4; ++i) ov[i] = (f32x4){0.f, 0.f, 0.f, 0.f};
    float m_run = -1e30f, l_run = 0.f;

    const int srow = tid >> 3;   // 0..31
    const int seg  = tid & 7;    // 16B segment

    const float SC = 0.125f * 1.44269504088896f;   // scale * log2(e)

    for (int jr = j0; jr < jmax; jr += 2) {
        const int nrow = min(jmax - jr, 2) * 64;   // 64 or 128 keys this round
        __syncthreads();   // all waves done reading previous round's Ks/Vs

#pragma unroll
        for (int r4 = 0; r4 < 4; ++r4) {
            int row = srow + r4 * 32;
            if (row < nrow)
                *(ulonglong2*)&Ks[row * LD + seg * 8] =
                    *(const ulonglong2*)&k_g[(size_t)(jr * 64 + row) * HH + seg * 8];
        }
#pragma unroll
        for (int c2 = 0; c2 < 2; ++c2) {
            int chunk = seg + c2 * 8;            // 0..15
            if (chunk * 8 < nrow) {
#pragma unroll
                for (int r2 = 0; r2 < 2; ++r2) {
                    int h = srow + r2 * 32;
                    *(ulonglong2*)&Vs[h * 136 + chunk * 8] =
                        *(const ulonglong2*)&vt_g[(size_t)h * TT + jr * 64 + chunk * 8];
                }
            }
        }
        __syncthreads();

        const int jend = min(jr + 2, jmax);
        for (int j = jr; j < jend; ++j) {
            const int tl = (j - jr) * 64;

            f32x4 st[4];
#pragma unroll
            for (int i = 0; i < 4; ++i) st[i] = (f32x4){0.f, 0.f, 0.f, 0.f};
#pragma unroll
            for (int kk = 0; kk < 2; ++kk)
#pragma unroll
                for (int mt = 0; mt < 4; ++mt) {
                    short8 a = *(const short8*)&Ks[(tl + mt * 16 + l15) * LD + kk * 32 + quad * 8];
                    st[mt] = __builtin_amdgcn_mfma_f32_16x16x32_bf16(a, qf[kk], st[mt], 0, 0, 0);
                }

#pragma unroll
            for (int mt = 0; mt < 4; ++mt)
#pragma unroll
                for (int r = 0; r < 4; ++r) st[mt][r] *= SC;
            if (j == qt) {
                int qg = wave * 16 + l15;
#pragma unroll
                for (int mt = 0; mt < 4; ++mt)
#pragma unroll
                    for (int r = 0; r < 4; ++r)
                        if (mt * 16 + quad * 4 + r > qg) st[mt][r] = -1e30f;
            }

            float mloc = -1e30f;
#pragma unroll
            for (int mt = 0; mt < 4; ++mt)
#pragma unroll
                for (int r = 0; r < 4; ++r) mloc = fmaxf(mloc, st[mt][r]);
            mloc = fmaxf(mloc, __shfl_xor(mloc, 16));
            mloc = fmaxf(mloc, __shfl_xor(mloc, 32));
            float m_new = fmaxf(m_run, mloc);
            float alpha = exp2f(m_run - m_new);
            m_run = m_new;

            float ssum = 0.f;
#pragma unroll
            for (int mt = 0; mt < 4; ++mt)
#pragma unroll
                for (int r = 0; r < 4; ++r) {
                    float p = exp2f(st[mt][r] - m_new);
                    st[mt][r] = p;
                    ssum += p;
                }
            ssum += __shfl_xor(ssum, 16);
            ssum += __shfl_xor(ssum, 32);
            l_run = l_run * alpha + ssum;

#pragma unroll
            for (int mt = 0; mt < 4; ++mt)
                *(unsigned long long*)&Pw[l15 * LD + mt * 16 + quad * 4] =
                    pack4(st[mt][0], st[mt][1], st[mt][2], st[mt][3]);

            float a4[4];
#pragma unroll
            for (int r = 0; r < 4; ++r) a4[r] = __shfl(alpha, quad * 4 + r);
#pragma unroll
            for (int ht = 0; ht < 4; ++ht)
#pragma unroll
                for (int r = 0; r < 4; ++r) ov[ht][r] *= a4[r];

#pragma unroll
            for (int kk = 0; kk < 2; ++kk) {
                short8 a = *(const short8*)&Pw[l15 * LD + kk * 32 + quad * 8];
#pragma unroll
                for (int ht = 0; ht < 4; ++ht) {
                    short8 bf = *(const short8*)&Vs[(ht * 16 + l15) * 136 + tl + kk * 32 + quad * 8];
                    ov[ht] = __builtin_amdgcn_mfma_f32_16x16x32_bf16(a, bf, ov[ht], 0, 0, 0);
                }
            }
        }
    }

    float* Ob = Opart + ((size_t)((b * 64 + qt) * NCH + c)) * 4096;
#pragma unroll
    for (int ht = 0; ht < 4; ++ht)
#pragma unroll
        for (int r = 0; r < 4; ++r)
            Ob[(size_t)(wave * 16 + quad * 4 + r) * HH + ht * 16 + l15] = ov[ht][r];
    if (quad == 0) {
        size_t mi = (size_t)((b * 64 + qt) * NCH + c) * 64 + wave * 16 + l15;
        Mpart[mi] = m_run;
        Lpart[mi] = l_run;
    }
}

// ---------------------------------------------------------------------------
// Kernel 3: combine partials (exp2 domain), normalize, write fp32 out.
// (proven R4/R6-R9, verbatim)
// ---------------------------------------------------------------------------
__global__ __launch_bounds__(256) void combine(
    const float* __restrict__ Opart,
    const float* __restrict__ Mpart,
    const float* __restrict__ Lpart,
    float* __restrict__ out)
{
    const int qt = blockIdx.x;
    const int b  = blockIdx.y;
    const int nc = (qt >> 4) + 1;
    const int t  = threadIdx.x;
    const int row = t >> 2;
    const int seg = t & 3;

    const size_t base = (size_t)(b * 64 + qt) * NCH;

    float m_c[NCH], M = -1e30f;
    for (int c = 0; c < nc; ++c) {
        m_c[c] = Mpart[(base + c) * 64 + row];
        M = fmaxf(M, m_c[c]);
    }
    float L = 0.f, w_c[NCH];
    for (int c = 0; c < nc; ++c) {
        w_c[c] = exp2f(m_c[c] - M);
        L += w_c[c] * Lpart[(base + c) * 64 + row];
    }
    float invL = 1.0f / L;

    f32x4 o[4];
#pragma unroll
    for (int i = 0; i < 4; ++i) o[i] = (f32x4){0.f, 0.f, 0.f, 0.f};
    for (int c = 0; c < nc; ++c) {
        const float* Ob = Opart + (base + c) * 4096 + (size_t)row * HH + seg * 16;
#pragma unroll
        for (int i = 0; i < 4; ++i) {
            f32x4 v = *(const f32x4*)(Ob + i * 4);
            o[i] += v * w_c[c];
        }
    }
    float* op = out + ((size_t)b * TT + qt * 64 + row) * HH + seg * 16;
#pragma unroll
    for (int i = 0; i < 4; ++i)
        *(f32x4*)(op + i * 4) = o[i] * invL;
}

extern "C" void kernel_launch(void* const* d_in, const int* in_sizes, int n_in,
                              void* d_out, int out_size, void* d_ws, size_t ws_size,
                              hipStream_t stream) {
    const float* x  = (const float*)d_in[0];
    const float* Wq = (const float*)d_in[1];
    const float* Wk = (const float*)d_in[2];
    const float* Wv = (const float*)d_in[3];
    float* out = (float*)d_out;

    unsigned short* qkv = (unsigned short*)d_ws;                 // 6.29 MB bf16
    float* Opart = (float*)((char*)d_ws + BF_TOTAL * 2);         // 16.78 MB fp32
    float* Mpart = Opart + (size_t)BB * 64 * NCH * 4096;         // 0.26 MB
    float* Lpart = Mpart + (size_t)BB * 64 * NCH * 64;           // 0.26 MB

    unsigned short* Wt = (unsigned short*)d_out;  // pre-scratch; combine overwrites

    transpose_w<<<dim3(16, 3), 256, 0, stream>>>(Wq, Wk, Wv, Wt);
    qkv_proj<<<dim3(MTOT / 32), 256, 0, stream>>>(x, Wt, qkv);
    flash_attn<<<dim3(64, BB, NCH), 256, 0, stream>>>(qkv, Opart, Mpart, Lpart);
    combine<<<dim3(64, BB), 256, 0, stream>>>(Opart, Mpart, Lpart, out);
}